// Round 3
// baseline (248.180 us; speedup 1.0000x reference)
//
#include <hip/hip_runtime.h>

// Problem constants from setup_inputs(): shape (64, 16, 64, 64), fp32, kern=2.
#define N_ 64
#define C_ 16
#define H_ 64
#define W_ 64

// pair_kernel decomposition: JT = 8 j's per block-group, D split into 4 chunks.
// tri sets (vaa, vbb): per i, j-tiles jt = 0..i/8 -> 288 groups/set
// vab (full):          64 i * 8 jt               -> 512 groups
#define TRI_BLOCKS 288
#define PAIR_GROUPS (2 * TRI_BLOCKS + 512)       // 1088
#define DSPLIT 4
#define PAIR_BLOCKS (PAIR_GROUPS * DSPLIT)       // 4352

// ws layout (floats): [0..Np) mu_a | [Np..2Np) var_a | [2Np..3Np) mu_b | [3Np..4Np) var_b

__global__ __launch_bounds__(256) void pool_kernel(
    const float* __restrict__ mu_a, const float* __restrict__ lv_a,
    const float* __restrict__ mu_b, const float* __restrict__ lv_b,
    const int* __restrict__ kern_p, float* __restrict__ ws,
    float* __restrict__ out) {
    if (blockIdx.x == 0 && threadIdx.x == 0) out[0] = 0.0f;  // pair runs after (stream order)

    const int k = kern_p[0];
    const float LOG2E = 1.44269504088896f;

    if (k == 2) {
        // Fast path: 4 contiguous pooled outputs per thread, all-shift indexing.
        const int Np = (N_ * C_ * H_ * W_) >> 2;  // 1048576
        const int Q  = Np >> 2;                   // 262144 quads per array
        const int total = 4 * Q;
        for (int g = blockIdx.x * blockDim.x + threadIdx.x; g < total;
             g += gridDim.x * blockDim.x) {
            const int a  = g >> 18;               // log2(Q) = 18
            const int r4 = g & (Q - 1);
            const int pw4 = (r4 & 7) << 2;        // Wp=32 -> 8 quads/row
            const int t   = r4 >> 3;
            const int ph  = t & 31;               // Hp=32
            const int nc  = t >> 5;
            const float* src = (a == 0) ? mu_a : (a == 1) ? lv_a : (a == 2) ? mu_b : lv_b;
            const bool is_var = (a & 1);
            const float* p0 = src + nc * (H_ * W_) + (ph * 2) * W_ + pw4 * 2;
            float4 r0a = *(const float4*)(p0);
            float4 r0b = *(const float4*)(p0 + 4);
            float4 r1a = *(const float4*)(p0 + W_);
            float4 r1b = *(const float4*)(p0 + W_ + 4);
            float o0, o1, o2, o3;
            if (is_var) {
#define E_(x) __builtin_amdgcn_exp2f((x) * LOG2E)
                o0 = E_(r0a.x) + E_(r0a.y) + E_(r1a.x) + E_(r1a.y);
                o1 = E_(r0a.z) + E_(r0a.w) + E_(r1a.z) + E_(r1a.w);
                o2 = E_(r0b.x) + E_(r0b.y) + E_(r1b.x) + E_(r1b.y);
                o3 = E_(r0b.z) + E_(r0b.w) + E_(r1b.z) + E_(r1b.w);
#undef E_
                const float s = 1.0f / 16.0f;     // 1/k^4
                o0 *= s; o1 *= s; o2 *= s; o3 *= s;
            } else {
                o0 = r0a.x + r0a.y + r1a.x + r1a.y;
                o1 = r0a.z + r0a.w + r1a.z + r1a.w;
                o2 = r0b.x + r0b.y + r1b.x + r1b.y;
                o3 = r0b.z + r0b.w + r1b.z + r1b.w;
                const float s = 0.25f;            // 1/k^2
                o0 *= s; o1 *= s; o2 *= s; o3 *= s;
            }
            *(float4*)(ws + (size_t)a * Np + (size_t)r4 * 4) = make_float4(o0, o1, o2, o3);
        }
    } else {
        // Generic fallback (any k dividing 64).
        const int Hp = H_ / k, Wp = W_ / k;
        const int Np = N_ * C_ * Hp * Wp;
        const float inv_k2 = 1.0f / (float)(k * k);
        const float inv_k4 = inv_k2 * inv_k2;
        const int total = 4 * Np;
        for (int p = blockIdx.x * blockDim.x + threadIdx.x; p < total;
             p += gridDim.x * blockDim.x) {
            const int a  = p / Np;
            const int r  = p - a * Np;
            const int pw = r % Wp;
            const int t1 = r / Wp;
            const int ph = t1 % Hp;
            const int nc = t1 / Hp;
            const float* src = (a == 0) ? mu_a : (a == 1) ? lv_a : (a == 2) ? mu_b : lv_b;
            const bool is_var = (a & 1);
            const int base = nc * (H_ * W_) + (ph * k) * W_ + (pw * k);
            float s = 0.0f;
            for (int dy = 0; dy < k; ++dy) {
                const float* row = src + base + dy * W_;
                for (int dx = 0; dx < k; ++dx) {
                    float x = row[dx];
                    s += is_var ? __builtin_amdgcn_exp2f(x * LOG2E) : x;
                }
            }
            ws[(size_t)a * Np + r] = s * (is_var ? inv_k4 : inv_k2);
        }
    }
}

// block = (set, i, jt, c): i-chunk held in registers, 8 j-rows streamed against it,
// D split into DSPLIT chunks across blocks for occupancy.
__global__ __launch_bounds__(256, 8) void pair_kernel(const float* __restrict__ ws,
                                                      const int* __restrict__ kern_p,
                                                      float* __restrict__ out) {
    const int k = kern_p[0];
    const int D  = C_ * (H_ / k) * (W_ / k);
    const int Np = N_ * D;

    const float* mu_a = ws;
    const float* va   = ws + (size_t)Np;
    const float* mu_b = ws + (size_t)2 * Np;
    const float* vb   = ws + (size_t)3 * Np;

    // ---- decode block -> (set, i, jt, c) ----
    const int pb = blockIdx.x >> 2;   // pair-group
    const int c  = blockIdx.x & 3;    // D-chunk
    int set, i, jt;
    if (pb >= 2 * TRI_BLOCKS) {
        set = 2;
        const int t = pb - 2 * TRI_BLOCKS;
        i  = t >> 3;
        jt = t & 7;
    } else {
        set = (pb >= TRI_BLOCKS) ? 1 : 0;
        const int t = (pb >= TRI_BLOCKS) ? (pb - TRI_BLOCKS) : pb;
        int g = 0;                    // i-group = i>>3; S(g)=4g(g+1) groups before
        while (g < 7 && 4 * (g + 1) * (g + 2) <= t) ++g;
        const int r = t - 4 * g * (g + 1);
        i  = 8 * g + r / (g + 1);
        jt = r % (g + 1);
    }

    const float *mu1, *v1, *mu2, *v2;
    if (set == 0)      { mu1 = mu2 = mu_a; v1 = v2 = va; }
    else if (set == 1) { mu1 = mu2 = mu_b; v1 = v2 = vb; }
    else               { mu1 = mu_a; v1 = va; mu2 = mu_b; v2 = vb; }

    const int j0 = jt * 8;
    float wgt[8];
    for (int j8 = 0; j8 < 8; ++j8) {
        if (set == 2) wgt[j8] = -2.0f;
        else {
            const int j = j0 + j8;
            wgt[j8] = (j > i) ? 0.0f : (j == i) ? 1.0f : 2.0f;
        }
    }

    const float NHALF_LOG2E = -0.721347520444482f;  // -0.5 * log2(e)
#define TERM(mx1, sx1, mx2, sx2)                                       \
    {                                                                  \
        float v  = (sx1) + (sx2);                                      \
        float rs = __builtin_amdgcn_rsqf(v);                           \
        float d  = (mx1) - (mx2);                                      \
        float t_ = d * rs;                                             \
        float e  = __builtin_amdgcn_exp2f((NHALF_LOG2E * t_) * t_);    \
        a = fmaf(e, rs, a);                                            \
    }

    float accs[8] = {0, 0, 0, 0, 0, 0, 0, 0};

    if (D == 16384) {
        // Fast path: this block handles D-chunk [c*4096, (c+1)*4096).
        // Thread holds 16 i-elems (4x float4, stride 1024 within the chunk).
        const int base = (c << 12) + (threadIdx.x << 2);
        const float* Mi = mu1 + (size_t)i * D + base;
        const float* Vi = v1  + (size_t)i * D + base;
        const float4 im0 = *(const float4*)(Mi);
        const float4 im1 = *(const float4*)(Mi + 1024);
        const float4 im2 = *(const float4*)(Mi + 2048);
        const float4 im3 = *(const float4*)(Mi + 3072);
        const float4 iv0 = *(const float4*)(Vi);
        const float4 iv1 = *(const float4*)(Vi + 1024);
        const float4 iv2 = *(const float4*)(Vi + 2048);
        const float4 iv3 = *(const float4*)(Vi + 3072);
        for (int j8 = 0; j8 < 8; ++j8) {
            const float* Mj = mu2 + (size_t)(j0 + j8) * D + base;
            const float* Vj = v2  + (size_t)(j0 + j8) * D + base;
            const float4 jm0 = *(const float4*)(Mj);
            const float4 jm1 = *(const float4*)(Mj + 1024);
            const float4 jm2 = *(const float4*)(Mj + 2048);
            const float4 jm3 = *(const float4*)(Mj + 3072);
            const float4 jv0 = *(const float4*)(Vj);
            const float4 jv1 = *(const float4*)(Vj + 1024);
            const float4 jv2 = *(const float4*)(Vj + 2048);
            const float4 jv3 = *(const float4*)(Vj + 3072);
            float a = 0.0f;
            TERM(im0.x, iv0.x, jm0.x, jv0.x) TERM(im0.y, iv0.y, jm0.y, jv0.y)
            TERM(im0.z, iv0.z, jm0.z, jv0.z) TERM(im0.w, iv0.w, jm0.w, jv0.w)
            TERM(im1.x, iv1.x, jm1.x, jv1.x) TERM(im1.y, iv1.y, jm1.y, jv1.y)
            TERM(im1.z, iv1.z, jm1.z, jv1.z) TERM(im1.w, iv1.w, jm1.w, jv1.w)
            TERM(im2.x, iv2.x, jm2.x, jv2.x) TERM(im2.y, iv2.y, jm2.y, jv2.y)
            TERM(im2.z, iv2.z, jm2.z, jv2.z) TERM(im2.w, iv2.w, jm2.w, jv2.w)
            TERM(im3.x, iv3.x, jm3.x, jv3.x) TERM(im3.y, iv3.y, jm3.y, jv3.y)
            TERM(im3.z, iv3.z, jm3.z, jv3.z) TERM(im3.w, iv3.w, jm3.w, jv3.w)
            accs[j8] += a;
        }
    } else {
        // Generic fallback: chunk c covers [c*D/4, (c+1)*D/4).
        const int lo = (c * D) >> 2, hi = ((c + 1) * D) >> 2;
        const float* Mi = mu1 + (size_t)i * D;
        const float* Vi = v1  + (size_t)i * D;
        for (int j8 = 0; j8 < 8; ++j8) {
            const float* Mj = mu2 + (size_t)(j0 + j8) * D;
            const float* Vj = v2  + (size_t)(j0 + j8) * D;
            float a = 0.0f;
            for (int e = lo + (int)threadIdx.x; e < hi; e += 256) {
                TERM(Mi[e], Vi[e], Mj[e], Vj[e])
            }
            accs[j8] = a;
        }
    }
#undef TERM

    float tot = 0.0f;
    for (int j8 = 0; j8 < 8; ++j8) tot += wgt[j8] * accs[j8];

    for (int off = 32; off > 0; off >>= 1)
        tot += __shfl_down(tot, off, 64);
    __shared__ float wsum[4];
    const int lane = threadIdx.x & 63;
    const int wid  = threadIdx.x >> 6;
    if (lane == 0) wsum[wid] = tot;
    __syncthreads();
    if (threadIdx.x == 0) {
        atomicAdd(out, wsum[0] + wsum[1] + wsum[2] + wsum[3]);
    }
}

extern "C" void kernel_launch(void* const* d_in, const int* in_sizes, int n_in,
                              void* d_out, int out_size, void* d_ws, size_t ws_size,
                              hipStream_t stream) {
    const float* mu_a = (const float*)d_in[0];
    const float* lv_a = (const float*)d_in[1];
    const float* mu_b = (const float*)d_in[2];
    const float* lv_b = (const float*)d_in[3];
    const int*   kern = (const int*)d_in[4];
    float* out = (float*)d_out;
    float* ws  = (float*)d_ws;

    pool_kernel<<<4096, 256, 0, stream>>>(mu_a, lv_a, mu_b, lv_b, kern, ws, out);
    pair_kernel<<<PAIR_BLOCKS, 256, 0, stream>>>(ws, kern, out);
}

// Round 4
// 165.068 us; speedup vs baseline: 1.5035x; 1.5035x over previous
//
#include <hip/hip_runtime.h>

// Problem constants from setup_inputs(): shape (64, 16, 64, 64), fp32, kern=2.
#define N_ 64
#define C_ 16
#define H_ 64
#define W_ 64

// pair_kernel decomposition: JT = 8 j's per block-group, D split into 4 chunks.
// tri sets (vaa, vbb): per i, j-tiles jt = 0..i/8 -> 288 groups/set
// vab (full):          64 i * 8 jt               -> 512 groups
#define TRI_BLOCKS 288
#define PAIR_GROUPS (2 * TRI_BLOCKS + 512)       // 1088
#define DSPLIT 4
#define PAIR_BLOCKS (PAIR_GROUPS * DSPLIT)       // 4352

// ws layout (floats): [0..Np) mu_a | [Np..2Np) var_a | [2Np..3Np) mu_b | [3Np..4Np) var_b

__global__ __launch_bounds__(256) void pool_kernel(
    const float* __restrict__ mu_a, const float* __restrict__ lv_a,
    const float* __restrict__ mu_b, const float* __restrict__ lv_b,
    const int* __restrict__ kern_p, float* __restrict__ ws,
    float* __restrict__ out) {
    if (blockIdx.x == 0 && threadIdx.x == 0) out[0] = 0.0f;  // pair runs after (stream order)

    const int k = kern_p[0];
    const float LOG2E = 1.44269504088896f;

    if (k == 2) {
        // Fast path: 4 contiguous pooled outputs per thread, all-shift indexing.
        const int Np = (N_ * C_ * H_ * W_) >> 2;  // 1048576
        const int Q  = Np >> 2;                   // 262144 quads per array
        const int total = 4 * Q;
        for (int g = blockIdx.x * blockDim.x + threadIdx.x; g < total;
             g += gridDim.x * blockDim.x) {
            const int a  = g >> 18;               // log2(Q) = 18
            const int r4 = g & (Q - 1);
            const int pw4 = (r4 & 7) << 2;        // Wp=32 -> 8 quads/row
            const int t   = r4 >> 3;
            const int ph  = t & 31;               // Hp=32
            const int nc  = t >> 5;
            const float* src = (a == 0) ? mu_a : (a == 1) ? lv_a : (a == 2) ? mu_b : lv_b;
            const bool is_var = (a & 1);
            const float* p0 = src + nc * (H_ * W_) + (ph * 2) * W_ + pw4 * 2;
            float4 r0a = *(const float4*)(p0);
            float4 r0b = *(const float4*)(p0 + 4);
            float4 r1a = *(const float4*)(p0 + W_);
            float4 r1b = *(const float4*)(p0 + W_ + 4);
            float o0, o1, o2, o3;
            if (is_var) {
#define E_(x) __builtin_amdgcn_exp2f((x) * LOG2E)
                o0 = E_(r0a.x) + E_(r0a.y) + E_(r1a.x) + E_(r1a.y);
                o1 = E_(r0a.z) + E_(r0a.w) + E_(r1a.z) + E_(r1a.w);
                o2 = E_(r0b.x) + E_(r0b.y) + E_(r1b.x) + E_(r1b.y);
                o3 = E_(r0b.z) + E_(r0b.w) + E_(r1b.z) + E_(r1b.w);
#undef E_
                const float s = 1.0f / 16.0f;     // 1/k^4
                o0 *= s; o1 *= s; o2 *= s; o3 *= s;
            } else {
                o0 = r0a.x + r0a.y + r1a.x + r1a.y;
                o1 = r0a.z + r0a.w + r1a.z + r1a.w;
                o2 = r0b.x + r0b.y + r1b.x + r1b.y;
                o3 = r0b.z + r0b.w + r1b.z + r1b.w;
                const float s = 0.25f;            // 1/k^2
                o0 *= s; o1 *= s; o2 *= s; o3 *= s;
            }
            *(float4*)(ws + (size_t)a * Np + (size_t)r4 * 4) = make_float4(o0, o1, o2, o3);
        }
    } else {
        // Generic fallback (any k dividing 64).
        const int Hp = H_ / k, Wp = W_ / k;
        const int Np = N_ * C_ * Hp * Wp;
        const float inv_k2 = 1.0f / (float)(k * k);
        const float inv_k4 = inv_k2 * inv_k2;
        const int total = 4 * Np;
        for (int p = blockIdx.x * blockDim.x + threadIdx.x; p < total;
             p += gridDim.x * blockDim.x) {
            const int a  = p / Np;
            const int r  = p - a * Np;
            const int pw = r % Wp;
            const int t1 = r / Wp;
            const int ph = t1 % Hp;
            const int nc = t1 / Hp;
            const float* src = (a == 0) ? mu_a : (a == 1) ? lv_a : (a == 2) ? mu_b : lv_b;
            const bool is_var = (a & 1);
            const int base = nc * (H_ * W_) + (ph * k) * W_ + (pw * k);
            float s = 0.0f;
            for (int dy = 0; dy < k; ++dy) {
                const float* row = src + base + dy * W_;
                for (int dx = 0; dx < k; ++dx) {
                    float x = row[dx];
                    s += is_var ? __builtin_amdgcn_exp2f(x * LOG2E) : x;
                }
            }
            ws[(size_t)a * Np + r] = s * (is_var ? inv_k4 : inv_k2);
        }
    }
}

// block = (set, i, jt, c): i-chunk held in registers, 8 j-rows streamed against it,
// D split into DSPLIT chunks across blocks for occupancy.
// NOTE: no min-waves clause — __launch_bounds__(256, 8) forced VGPR<=64 and
// spilled (R3: WRITE_SIZE 34KB -> 100MB, 2x regression). Natural alloc ~48-64
// VGPRs already permits 8 waves/SIMD.
__global__ __launch_bounds__(256) void pair_kernel(const float* __restrict__ ws,
                                                   const int* __restrict__ kern_p,
                                                   float* __restrict__ out) {
    const int k = kern_p[0];
    const int D  = C_ * (H_ / k) * (W_ / k);
    const int Np = N_ * D;

    const float* mu_a = ws;
    const float* va   = ws + (size_t)Np;
    const float* mu_b = ws + (size_t)2 * Np;
    const float* vb   = ws + (size_t)3 * Np;

    // ---- decode block -> (set, i, jt, c) ----
    const int pb = blockIdx.x >> 2;   // pair-group
    const int c  = blockIdx.x & 3;    // D-chunk
    int set, i, jt;
    if (pb >= 2 * TRI_BLOCKS) {
        set = 2;
        const int t = pb - 2 * TRI_BLOCKS;
        i  = t >> 3;
        jt = t & 7;
    } else {
        set = (pb >= TRI_BLOCKS) ? 1 : 0;
        const int t = (pb >= TRI_BLOCKS) ? (pb - TRI_BLOCKS) : pb;
        int g = 0;                    // i-group = i>>3; S(g)=4g(g+1) groups before
        while (g < 7 && 4 * (g + 1) * (g + 2) <= t) ++g;
        const int r = t - 4 * g * (g + 1);
        i  = 8 * g + r / (g + 1);
        jt = r % (g + 1);
    }

    const float *mu1, *v1, *mu2, *v2;
    if (set == 0)      { mu1 = mu2 = mu_a; v1 = v2 = va; }
    else if (set == 1) { mu1 = mu2 = mu_b; v1 = v2 = vb; }
    else               { mu1 = mu_a; v1 = va; mu2 = mu_b; v2 = vb; }

    const int j0 = jt * 8;
    float wgt[8];
    for (int j8 = 0; j8 < 8; ++j8) {
        if (set == 2) wgt[j8] = -2.0f;
        else {
            const int j = j0 + j8;
            wgt[j8] = (j > i) ? 0.0f : (j == i) ? 1.0f : 2.0f;
        }
    }

    const float NHALF_LOG2E = -0.721347520444482f;  // -0.5 * log2(e)
#define TERM(mx1, sx1, mx2, sx2)                                       \
    {                                                                  \
        float v  = (sx1) + (sx2);                                      \
        float rs = __builtin_amdgcn_rsqf(v);                           \
        float d  = (mx1) - (mx2);                                      \
        float t_ = d * rs;                                             \
        float e  = __builtin_amdgcn_exp2f((NHALF_LOG2E * t_) * t_);    \
        a = fmaf(e, rs, a);                                            \
    }

    float accs[8] = {0, 0, 0, 0, 0, 0, 0, 0};

    if (D == 16384) {
        // Fast path: this block handles D-chunk [c*4096, (c+1)*4096).
        // Thread holds 16 i-elems (4x float4, stride 1024 within the chunk).
        const int base = (c << 12) + (threadIdx.x << 2);
        const float* Mi = mu1 + (size_t)i * D + base;
        const float* Vi = v1  + (size_t)i * D + base;
        const float4 im0 = *(const float4*)(Mi);
        const float4 im1 = *(const float4*)(Mi + 1024);
        const float4 im2 = *(const float4*)(Mi + 2048);
        const float4 im3 = *(const float4*)(Mi + 3072);
        const float4 iv0 = *(const float4*)(Vi);
        const float4 iv1 = *(const float4*)(Vi + 1024);
        const float4 iv2 = *(const float4*)(Vi + 2048);
        const float4 iv3 = *(const float4*)(Vi + 3072);
        for (int j8 = 0; j8 < 8; ++j8) {
            const float* Mj = mu2 + (size_t)(j0 + j8) * D + base;
            const float* Vj = v2  + (size_t)(j0 + j8) * D + base;
            const float4 jm0 = *(const float4*)(Mj);
            const float4 jm1 = *(const float4*)(Mj + 1024);
            const float4 jm2 = *(const float4*)(Mj + 2048);
            const float4 jm3 = *(const float4*)(Mj + 3072);
            const float4 jv0 = *(const float4*)(Vj);
            const float4 jv1 = *(const float4*)(Vj + 1024);
            const float4 jv2 = *(const float4*)(Vj + 2048);
            const float4 jv3 = *(const float4*)(Vj + 3072);
            float a = 0.0f;
            TERM(im0.x, iv0.x, jm0.x, jv0.x) TERM(im0.y, iv0.y, jm0.y, jv0.y)
            TERM(im0.z, iv0.z, jm0.z, jv0.z) TERM(im0.w, iv0.w, jm0.w, jv0.w)
            TERM(im1.x, iv1.x, jm1.x, jv1.x) TERM(im1.y, iv1.y, jm1.y, jv1.y)
            TERM(im1.z, iv1.z, jm1.z, jv1.z) TERM(im1.w, iv1.w, jm1.w, jv1.w)
            TERM(im2.x, iv2.x, jm2.x, jv2.x) TERM(im2.y, iv2.y, jm2.y, jv2.y)
            TERM(im2.z, iv2.z, jm2.z, jv2.z) TERM(im2.w, iv2.w, jm2.w, jv2.w)
            TERM(im3.x, iv3.x, jm3.x, jv3.x) TERM(im3.y, iv3.y, jm3.y, jv3.y)
            TERM(im3.z, iv3.z, jm3.z, jv3.z) TERM(im3.w, iv3.w, jm3.w, jv3.w)
            accs[j8] += a;
        }
    } else {
        // Generic fallback: chunk c covers [c*D/4, (c+1)*D/4).
        const int lo = (c * D) >> 2, hi = ((c + 1) * D) >> 2;
        const float* Mi = mu1 + (size_t)i * D;
        const float* Vi = v1  + (size_t)i * D;
        for (int j8 = 0; j8 < 8; ++j8) {
            const float* Mj = mu2 + (size_t)(j0 + j8) * D;
            const float* Vj = v2  + (size_t)(j0 + j8) * D;
            float a = 0.0f;
            for (int e = lo + (int)threadIdx.x; e < hi; e += 256) {
                TERM(Mi[e], Vi[e], Mj[e], Vj[e])
            }
            accs[j8] = a;
        }
    }
#undef TERM

    float tot = 0.0f;
    for (int j8 = 0; j8 < 8; ++j8) tot += wgt[j8] * accs[j8];

    for (int off = 32; off > 0; off >>= 1)
        tot += __shfl_down(tot, off, 64);
    __shared__ float wsum[4];
    const int lane = threadIdx.x & 63;
    const int wid  = threadIdx.x >> 6;
    if (lane == 0) wsum[wid] = tot;
    __syncthreads();
    if (threadIdx.x == 0) {
        atomicAdd(out, wsum[0] + wsum[1] + wsum[2] + wsum[3]);
    }
}

extern "C" void kernel_launch(void* const* d_in, const int* in_sizes, int n_in,
                              void* d_out, int out_size, void* d_ws, size_t ws_size,
                              hipStream_t stream) {
    const float* mu_a = (const float*)d_in[0];
    const float* lv_a = (const float*)d_in[1];
    const float* mu_b = (const float*)d_in[2];
    const float* lv_b = (const float*)d_in[3];
    const int*   kern = (const int*)d_in[4];
    float* out = (float*)d_out;
    float* ws  = (float*)d_ws;

    pool_kernel<<<4096, 256, 0, stream>>>(mu_a, lv_a, mu_b, lv_b, kern, ws, out);
    pair_kernel<<<PAIR_BLOCKS, 256, 0, stream>>>(ws, kern, out);
}

// Round 5
// 160.065 us; speedup vs baseline: 1.5505x; 1.0313x over previous
//
#include <hip/hip_runtime.h>

// Problem constants from setup_inputs(): shape (64, 16, 64, 64), fp32, kern=2.
#define N_ 64
#define C_ 16
#define H_ 64
#define W_ 64

// pair_kernel tiling: 4 i-rows x 8 j-rows per tile, D split into 16 chunks.
// tri sets (vaa, vbb): i-tile g (rows 4g..4g+3) needs j-tiles 0..(g>>1)
//   -> sum over g=0..15 of (g>>1)+1 = 72 tiles per set
// vab (full): 16 i-tiles x 8 j-tiles = 128 tiles. TILES = 72*2 + 128 = 272.
// blockIdx = t*16 + c  => XCD = bx%8 = c%8: each XCD's L2 sees 2 chunk-columns
// (2 MB of the 16 MB ws) -> L2-resident j-stream.
#define TRI_TILES 72
#define TILES 272
#define DCHUNKS 16
#define PAIR_BLOCKS (TILES * DCHUNKS)   // 4352

// ws layout (floats): [0..Np) mu_a | [Np..2Np) var_a | [2Np..3Np) mu_b | [3Np..4Np) var_b

__global__ __launch_bounds__(256) void pool_kernel(
    const float* __restrict__ mu_a, const float* __restrict__ lv_a,
    const float* __restrict__ mu_b, const float* __restrict__ lv_b,
    const int* __restrict__ kern_p, float* __restrict__ ws,
    float* __restrict__ out) {
    if (blockIdx.x == 0 && threadIdx.x == 0) out[0] = 0.0f;  // pair runs after (stream order)

    const int k = kern_p[0];
    const float LOG2E = 1.44269504088896f;

    if (k == 2) {
        // Fast path: 4 contiguous pooled outputs per thread, all-shift indexing.
        const int Np = (N_ * C_ * H_ * W_) >> 2;  // 1048576
        const int Q  = Np >> 2;                   // 262144 quads per array
        const int total = 4 * Q;
        for (int g = blockIdx.x * blockDim.x + threadIdx.x; g < total;
             g += gridDim.x * blockDim.x) {
            const int a  = g >> 18;               // log2(Q) = 18
            const int r4 = g & (Q - 1);
            const int pw4 = (r4 & 7) << 2;        // Wp=32 -> 8 quads/row
            const int t   = r4 >> 3;
            const int ph  = t & 31;               // Hp=32
            const int nc  = t >> 5;
            const float* src = (a == 0) ? mu_a : (a == 1) ? lv_a : (a == 2) ? mu_b : lv_b;
            const bool is_var = (a & 1);
            const float* p0 = src + nc * (H_ * W_) + (ph * 2) * W_ + pw4 * 2;
            float4 r0a = *(const float4*)(p0);
            float4 r0b = *(const float4*)(p0 + 4);
            float4 r1a = *(const float4*)(p0 + W_);
            float4 r1b = *(const float4*)(p0 + W_ + 4);
            float o0, o1, o2, o3;
            if (is_var) {
#define E_(x) __builtin_amdgcn_exp2f((x) * LOG2E)
                o0 = E_(r0a.x) + E_(r0a.y) + E_(r1a.x) + E_(r1a.y);
                o1 = E_(r0a.z) + E_(r0a.w) + E_(r1a.z) + E_(r1a.w);
                o2 = E_(r0b.x) + E_(r0b.y) + E_(r1b.x) + E_(r1b.y);
                o3 = E_(r0b.z) + E_(r0b.w) + E_(r1b.z) + E_(r1b.w);
#undef E_
                const float s = 1.0f / 16.0f;     // 1/k^4
                o0 *= s; o1 *= s; o2 *= s; o3 *= s;
            } else {
                o0 = r0a.x + r0a.y + r1a.x + r1a.y;
                o1 = r0a.z + r0a.w + r1a.z + r1a.w;
                o2 = r0b.x + r0b.y + r1b.x + r1b.y;
                o3 = r0b.z + r0b.w + r1b.z + r1b.w;
                const float s = 0.25f;            // 1/k^2
                o0 *= s; o1 *= s; o2 *= s; o3 *= s;
            }
            *(float4*)(ws + (size_t)a * Np + (size_t)r4 * 4) = make_float4(o0, o1, o2, o3);
        }
    } else {
        // Generic fallback (any k dividing 64).
        const int Hp = H_ / k, Wp = W_ / k;
        const int Np = N_ * C_ * Hp * Wp;
        const float inv_k2 = 1.0f / (float)(k * k);
        const float inv_k4 = inv_k2 * inv_k2;
        const int total = 4 * Np;
        for (int p = blockIdx.x * blockDim.x + threadIdx.x; p < total;
             p += gridDim.x * blockDim.x) {
            const int a  = p / Np;
            const int r  = p - a * Np;
            const int pw = r % Wp;
            const int t1 = r / Wp;
            const int ph = t1 % Hp;
            const int nc = t1 / Hp;
            const float* src = (a == 0) ? mu_a : (a == 1) ? lv_a : (a == 2) ? mu_b : lv_b;
            const bool is_var = (a & 1);
            const int base = nc * (H_ * W_) + (ph * k) * W_ + (pw * k);
            float s = 0.0f;
            for (int dy = 0; dy < k; ++dy) {
                const float* row = src + base + dy * W_;
                for (int dx = 0; dx < k; ++dx) {
                    float x = row[dx];
                    s += is_var ? __builtin_amdgcn_exp2f(x * LOG2E) : x;
                }
            }
            ws[(size_t)a * Np + r] = s * (is_var ? inv_k4 : inv_k2);
        }
    }
}

// block = (tile t, chunk c): 4 i-rows register-resident (1 float4 mu + var each),
// 8 j-rows streamed (1 float4 mu + var per j per chunk). 3 B/term of L2 traffic.
// NOTE: no min-waves clause — R3 showed __launch_bounds__(256,8) forces spills.
__global__ __launch_bounds__(256) void pair_kernel(const float* __restrict__ ws,
                                                   const int* __restrict__ kern_p,
                                                   float* __restrict__ out) {
    const int k = kern_p[0];
    const int D  = C_ * (H_ / k) * (W_ / k);
    const int Np = N_ * D;

    const float* mu_a = ws;
    const float* va   = ws + (size_t)Np;
    const float* mu_b = ws + (size_t)2 * Np;
    const float* vb   = ws + (size_t)3 * Np;

    // ---- decode block -> (set, i-tile, j-tile, chunk) ----
    const int c = blockIdx.x & (DCHUNKS - 1);
    const int t = blockIdx.x >> 4;           // DCHUNKS == 16
    int set, it, jt;
    if (t >= 2 * TRI_TILES) {
        set = 2;
        const int tt = t - 2 * TRI_TILES;
        it = tt >> 3;
        jt = tt & 7;
    } else {
        set = (t >= TRI_TILES) ? 1 : 0;
        const int tt = set ? (t - TRI_TILES) : t;
        int g = 0, cum = 0;
        while (cum + (g >> 1) + 1 <= tt) { cum += (g >> 1) + 1; ++g; }
        it = g;
        jt = tt - cum;
    }
    const int i0 = it * 4, j0 = jt * 8;

    const float *mu1, *v1, *mu2, *v2;
    if (set == 0)      { mu1 = mu2 = mu_a; v1 = v2 = va; }
    else if (set == 1) { mu1 = mu2 = mu_b; v1 = v2 = vb; }
    else               { mu1 = mu_a; v1 = va; mu2 = mu_b; v2 = vb; }

    const float NHALF_LOG2E = -0.721347520444482f;  // -0.5 * log2(e)
#define TERM(acc, mx1, sx1, mx2, sx2)                                  \
    {                                                                  \
        float v  = (sx1) + (sx2);                                      \
        float rs = __builtin_amdgcn_rsqf(v);                           \
        float d  = (mx1) - (mx2);                                      \
        float t_ = d * rs;                                             \
        float e  = __builtin_amdgcn_exp2f((NHALF_LOG2E * t_) * t_);    \
        acc = fmaf(e, rs, acc);                                        \
    }

    float accs[4][8];
    #pragma unroll
    for (int ir = 0; ir < 4; ++ir)
        #pragma unroll
        for (int j8 = 0; j8 < 8; ++j8) accs[ir][j8] = 0.0f;

    if (D == 16384) {
        // Fast path: chunk = 1024 elems = 256 threads x 1 float4.
        const int base = (c << 10) + ((int)threadIdx.x << 2);
        float4 im[4], iv[4];
        #pragma unroll
        for (int ir = 0; ir < 4; ++ir) {
            im[ir] = *(const float4*)(mu1 + (size_t)(i0 + ir) * 16384 + base);
            iv[ir] = *(const float4*)(v1  + (size_t)(i0 + ir) * 16384 + base);
        }
        #pragma unroll
        for (int j8 = 0; j8 < 8; ++j8) {
            const float4 jm = *(const float4*)(mu2 + (size_t)(j0 + j8) * 16384 + base);
            const float4 jv = *(const float4*)(v2  + (size_t)(j0 + j8) * 16384 + base);
            #pragma unroll
            for (int ir = 0; ir < 4; ++ir) {
                TERM(accs[ir][j8], im[ir].x, iv[ir].x, jm.x, jv.x)
                TERM(accs[ir][j8], im[ir].y, iv[ir].y, jm.y, jv.y)
                TERM(accs[ir][j8], im[ir].z, iv[ir].z, jm.z, jv.z)
                TERM(accs[ir][j8], im[ir].w, iv[ir].w, jm.w, jv.w)
            }
        }
    } else {
        // Generic fallback: chunk c covers [c*D/16, (c+1)*D/16), scalar loads.
        const int cs = D / DCHUNKS;
        const int lo = c * cs, hi = lo + cs;
        for (int e = lo + (int)threadIdx.x; e < hi; e += 256) {
            #pragma unroll
            for (int j8 = 0; j8 < 8; ++j8) {
                const float mj = mu2[(size_t)(j0 + j8) * D + e];
                const float vj = v2 [(size_t)(j0 + j8) * D + e];
                #pragma unroll
                for (int ir = 0; ir < 4; ++ir) {
                    const float mi = mu1[(size_t)(i0 + ir) * D + e];
                    const float vi = v1 [(size_t)(i0 + ir) * D + e];
                    TERM(accs[ir][j8], mi, vi, mj, vj)
                }
            }
        }
    }
#undef TERM

    float tot = 0.0f;
    #pragma unroll
    for (int ir = 0; ir < 4; ++ir) {
        #pragma unroll
        for (int j8 = 0; j8 < 8; ++j8) {
            float w;
            if (set == 2) w = -2.0f;
            else {
                const int ii = i0 + ir, jj = j0 + j8;
                w = (jj > ii) ? 0.0f : (jj == ii) ? 1.0f : 2.0f;
            }
            tot = fmaf(w, accs[ir][j8], tot);
        }
    }

    for (int off = 32; off > 0; off >>= 1)
        tot += __shfl_down(tot, off, 64);
    __shared__ float wsum[4];
    const int lane = threadIdx.x & 63;
    const int wid  = threadIdx.x >> 6;
    if (lane == 0) wsum[wid] = tot;
    __syncthreads();
    if (threadIdx.x == 0) {
        atomicAdd(out, wsum[0] + wsum[1] + wsum[2] + wsum[3]);
    }
}

extern "C" void kernel_launch(void* const* d_in, const int* in_sizes, int n_in,
                              void* d_out, int out_size, void* d_ws, size_t ws_size,
                              hipStream_t stream) {
    const float* mu_a = (const float*)d_in[0];
    const float* lv_a = (const float*)d_in[1];
    const float* mu_b = (const float*)d_in[2];
    const float* lv_b = (const float*)d_in[3];
    const int*   kern = (const int*)d_in[4];
    float* out = (float*)d_out;
    float* ws  = (float*)d_ws;

    pool_kernel<<<4096, 256, 0, stream>>>(mu_a, lv_a, mu_b, lv_b, kern, ws, out);
    pair_kernel<<<PAIR_BLOCKS, 256, 0, stream>>>(ws, kern, out);
}

// Round 6
// 159.419 us; speedup vs baseline: 1.5568x; 1.0041x over previous
//
#include <hip/hip_runtime.h>

// Problem constants from setup_inputs(): shape (64, 16, 64, 64), fp32, kern=2.
#define N_ 64
#define C_ 16
#define H_ 64
#define W_ 64

// pair_kernel tiling: 4 i-rows x 8 j-rows per tile, D split into 16 chunks.
// tri sets (vaa, vbb): i-tile g (rows 4g..4g+3) needs j-tiles 0..(g>>1)
//   -> sum over g=0..15 of (g>>1)+1 = 72 tiles per set
// vab (full): 16 i-tiles x 8 j-tiles = 128 tiles. TILES = 72*2 + 128 = 272.
// blockIdx = t*16 + c  => XCD = bx%8 = c%8: each XCD's L2 sees 2 chunk-columns.
#define TRI_TILES 72
#define TILES 272
#define DCHUNKS 16
#define PAIR_BLOCKS (TILES * DCHUNKS)   // 4352

// NUMERICS: ws stores var' = var * 2ln2. Then exp(-0.5 d^2/v)/sqrt(v)
//   = exp2(-(d*rsq(v'))^2) * rsq(v') * sqrt(2ln2),
// so each term needs only 5 VALU + 2 transc; sqrt(2ln2)=1.1774100 folds into
// the final scalar.
#define TWO_LN2   1.3862943611198906f
#define SQRT_2LN2 1.1774100225154747f

// ws layout (floats): [0..Np) mu_a | [Np..2Np) var'_a | [2Np..3Np) mu_b | [3Np..4Np) var'_b

__global__ __launch_bounds__(256) void pool_kernel(
    const float* __restrict__ mu_a, const float* __restrict__ lv_a,
    const float* __restrict__ mu_b, const float* __restrict__ lv_b,
    const int* __restrict__ kern_p, float* __restrict__ ws,
    float* __restrict__ out) {
    if (blockIdx.x == 0 && threadIdx.x == 0) out[0] = 0.0f;  // pair runs after (stream order)

    const int k = kern_p[0];
    const float LOG2E = 1.44269504088896f;

    if (k == 2) {
        // Fast path: 4 contiguous pooled outputs per thread, all-shift indexing.
        const int Np = (N_ * C_ * H_ * W_) >> 2;  // 1048576
        const int Q  = Np >> 2;                   // 262144 quads per array
        const int total = 4 * Q;
        for (int g = blockIdx.x * blockDim.x + threadIdx.x; g < total;
             g += gridDim.x * blockDim.x) {
            const int a  = g >> 18;               // log2(Q) = 18
            const int r4 = g & (Q - 1);
            const int pw4 = (r4 & 7) << 2;        // Wp=32 -> 8 quads/row
            const int t   = r4 >> 3;
            const int ph  = t & 31;               // Hp=32
            const int nc  = t >> 5;
            const float* src = (a == 0) ? mu_a : (a == 1) ? lv_a : (a == 2) ? mu_b : lv_b;
            const bool is_var = (a & 1);
            const float* p0 = src + nc * (H_ * W_) + (ph * 2) * W_ + pw4 * 2;
            float4 r0a = *(const float4*)(p0);
            float4 r0b = *(const float4*)(p0 + 4);
            float4 r1a = *(const float4*)(p0 + W_);
            float4 r1b = *(const float4*)(p0 + W_ + 4);
            float o0, o1, o2, o3;
            if (is_var) {
#define E_(x) __builtin_amdgcn_exp2f((x) * LOG2E)
                o0 = E_(r0a.x) + E_(r0a.y) + E_(r1a.x) + E_(r1a.y);
                o1 = E_(r0a.z) + E_(r0a.w) + E_(r1a.z) + E_(r1a.w);
                o2 = E_(r0b.x) + E_(r0b.y) + E_(r1b.x) + E_(r1b.y);
                o3 = E_(r0b.z) + E_(r0b.w) + E_(r1b.z) + E_(r1b.w);
#undef E_
                const float s = (1.0f / 16.0f) * TWO_LN2;  // 1/k^4 * 2ln2
                o0 *= s; o1 *= s; o2 *= s; o3 *= s;
            } else {
                o0 = r0a.x + r0a.y + r1a.x + r1a.y;
                o1 = r0a.z + r0a.w + r1a.z + r1a.w;
                o2 = r0b.x + r0b.y + r1b.x + r1b.y;
                o3 = r0b.z + r0b.w + r1b.z + r1b.w;
                const float s = 0.25f;            // 1/k^2
                o0 *= s; o1 *= s; o2 *= s; o3 *= s;
            }
            *(float4*)(ws + (size_t)a * Np + (size_t)r4 * 4) = make_float4(o0, o1, o2, o3);
        }
    } else {
        // Generic fallback (any k dividing 64).
        const int Hp = H_ / k, Wp = W_ / k;
        const int Np = N_ * C_ * Hp * Wp;
        const float inv_k2 = 1.0f / (float)(k * k);
        const float inv_k4 = inv_k2 * inv_k2 * TWO_LN2;   // fold var pre-scale
        const int total = 4 * Np;
        for (int p = blockIdx.x * blockDim.x + threadIdx.x; p < total;
             p += gridDim.x * blockDim.x) {
            const int a  = p / Np;
            const int r  = p - a * Np;
            const int pw = r % Wp;
            const int t1 = r / Wp;
            const int ph = t1 % Hp;
            const int nc = t1 / Hp;
            const float* src = (a == 0) ? mu_a : (a == 1) ? lv_a : (a == 2) ? mu_b : lv_b;
            const bool is_var = (a & 1);
            const int base = nc * (H_ * W_) + (ph * k) * W_ + (pw * k);
            float s = 0.0f;
            for (int dy = 0; dy < k; ++dy) {
                const float* row = src + base + dy * W_;
                for (int dx = 0; dx < k; ++dx) {
                    float x = row[dx];
                    s += is_var ? __builtin_amdgcn_exp2f(x * LOG2E) : x;
                }
            }
            ws[(size_t)a * Np + r] = s * (is_var ? inv_k4 : inv_k2);
        }
    }
}

// block = (tile t, chunk c): 4 i-rows register-resident (1 float4 mu + var' each),
// 8 j-rows streamed. Per term: add, rsq, sub, mul, mul, exp2(-u), fma = 5V + 2T.
// NOTE: no min-waves clause — R3 showed __launch_bounds__(256,8) forces spills.
__global__ __launch_bounds__(256) void pair_kernel(const float* __restrict__ ws,
                                                   const int* __restrict__ kern_p,
                                                   float* __restrict__ out) {
    const int k = kern_p[0];
    const int D  = C_ * (H_ / k) * (W_ / k);
    const int Np = N_ * D;

    const float* mu_a = ws;
    const float* va   = ws + (size_t)Np;
    const float* mu_b = ws + (size_t)2 * Np;
    const float* vb   = ws + (size_t)3 * Np;

    // ---- decode block -> (set, i-tile, j-tile, chunk) ----
    const int c = blockIdx.x & (DCHUNKS - 1);
    const int t = blockIdx.x >> 4;           // DCHUNKS == 16
    int set, it, jt;
    if (t >= 2 * TRI_TILES) {
        set = 2;
        const int tt = t - 2 * TRI_TILES;
        it = tt >> 3;
        jt = tt & 7;
    } else {
        set = (t >= TRI_TILES) ? 1 : 0;
        const int tt = set ? (t - TRI_TILES) : t;
        int g = 0, cum = 0;
        while (cum + (g >> 1) + 1 <= tt) { cum += (g >> 1) + 1; ++g; }
        it = g;
        jt = tt - cum;
    }
    const int i0 = it * 4, j0 = jt * 8;

    const float *mu1, *v1, *mu2, *v2;
    if (set == 0)      { mu1 = mu2 = mu_a; v1 = v2 = va; }
    else if (set == 1) { mu1 = mu2 = mu_b; v1 = v2 = vb; }
    else               { mu1 = mu_a; v1 = va; mu2 = mu_b; v2 = vb; }

#define TERM(acc, mx1, sx1, mx2, sx2)                                  \
    {                                                                  \
        float v  = (sx1) + (sx2);                                      \
        float rs = __builtin_amdgcn_rsqf(v);                           \
        float d  = (mx1) - (mx2);                                      \
        float t_ = d * rs;                                             \
        float e  = __builtin_amdgcn_exp2f(-(t_ * t_));                 \
        acc = fmaf(e, rs, acc);                                        \
    }

    float accs[4][8];
    #pragma unroll
    for (int ir = 0; ir < 4; ++ir)
        #pragma unroll
        for (int j8 = 0; j8 < 8; ++j8) accs[ir][j8] = 0.0f;

    if (D == 16384) {
        // Fast path: chunk = 1024 elems = 256 threads x 1 float4.
        const int base = (c << 10) + ((int)threadIdx.x << 2);
        float4 im[4], iv[4];
        #pragma unroll
        for (int ir = 0; ir < 4; ++ir) {
            im[ir] = *(const float4*)(mu1 + (size_t)(i0 + ir) * 16384 + base);
            iv[ir] = *(const float4*)(v1  + (size_t)(i0 + ir) * 16384 + base);
        }
        #pragma unroll
        for (int j8 = 0; j8 < 8; ++j8) {
            const float4 jm = *(const float4*)(mu2 + (size_t)(j0 + j8) * 16384 + base);
            const float4 jv = *(const float4*)(v2  + (size_t)(j0 + j8) * 16384 + base);
            #pragma unroll
            for (int ir = 0; ir < 4; ++ir) {
                TERM(accs[ir][j8], im[ir].x, iv[ir].x, jm.x, jv.x)
                TERM(accs[ir][j8], im[ir].y, iv[ir].y, jm.y, jv.y)
                TERM(accs[ir][j8], im[ir].z, iv[ir].z, jm.z, jv.z)
                TERM(accs[ir][j8], im[ir].w, iv[ir].w, jm.w, jv.w)
            }
        }
    } else {
        // Generic fallback: chunk c covers [c*D/16, (c+1)*D/16), scalar loads.
        const int cs = D / DCHUNKS;
        const int lo = c * cs, hi = lo + cs;
        for (int e = lo + (int)threadIdx.x; e < hi; e += 256) {
            #pragma unroll
            for (int j8 = 0; j8 < 8; ++j8) {
                const float mj = mu2[(size_t)(j0 + j8) * D + e];
                const float vj = v2 [(size_t)(j0 + j8) * D + e];
                #pragma unroll
                for (int ir = 0; ir < 4; ++ir) {
                    const float mi = mu1[(size_t)(i0 + ir) * D + e];
                    const float vi = v1 [(size_t)(i0 + ir) * D + e];
                    TERM(accs[ir][j8], mi, vi, mj, vj)
                }
            }
        }
    }
#undef TERM

    float tot = 0.0f;
    #pragma unroll
    for (int ir = 0; ir < 4; ++ir) {
        #pragma unroll
        for (int j8 = 0; j8 < 8; ++j8) {
            float w;
            if (set == 2) w = -2.0f;
            else {
                const int ii = i0 + ir, jj = j0 + j8;
                w = (jj > ii) ? 0.0f : (jj == ii) ? 1.0f : 2.0f;
            }
            tot = fmaf(w, accs[ir][j8], tot);
        }
    }
    tot *= SQRT_2LN2;   // fold the var'-prescale correction once

    for (int off = 32; off > 0; off >>= 1)
        tot += __shfl_down(tot, off, 64);
    __shared__ float wsum[4];
    const int lane = threadIdx.x & 63;
    const int wid  = threadIdx.x >> 6;
    if (lane == 0) wsum[wid] = tot;
    __syncthreads();
    if (threadIdx.x == 0) {
        atomicAdd(out, wsum[0] + wsum[1] + wsum[2] + wsum[3]);
    }
}

extern "C" void kernel_launch(void* const* d_in, const int* in_sizes, int n_in,
                              void* d_out, int out_size, void* d_ws, size_t ws_size,
                              hipStream_t stream) {
    const float* mu_a = (const float*)d_in[0];
    const float* lv_a = (const float*)d_in[1];
    const float* mu_b = (const float*)d_in[2];
    const float* lv_b = (const float*)d_in[3];
    const int*   kern = (const int*)d_in[4];
    float* out = (float*)d_out;
    float* ws  = (float*)d_ws;

    pool_kernel<<<4096, 256, 0, stream>>>(mu_a, lv_a, mu_b, lv_b, kern, ws, out);
    pair_kernel<<<PAIR_BLOCKS, 256, 0, stream>>>(ws, kern, out);
}